// Round 1
// 180.205 us; speedup vs baseline: 1.0009x; 1.0009x over previous
//
#include <hip/hip_runtime.h>
#include <math.h>

#define H   2048
#define SW  256
#define SD  200
#define GIN (H + SW)   // 2304
#define G3H (3 * H)    // 6144
#define OO  128

// ws float offsets
// word 0: done-counter (unsigned), zeroed by k_main each iteration
#define STOP_OFF 8
#define GI_OFF   512                  // gi_emb = W_ih[:, :H] @ x + b_ih   (6144)
#define GH_OFF   (GI_OFF + G3H)      // gh     = W_hh @ h + b_hh          (6144)
#define GIS_OFF  (GH_OFF + G3H)      // gi_stk = W_ih[:, H:] @ stack_top  (6144)

__device__ __forceinline__ float wave_reduce(float v) {
#pragma unroll
    for (int off = 32; off > 0; off >>= 1)
        v += __shfl_down(v, off, 64);
    return v;
}

__device__ __forceinline__ float sigmoidf(float x) {
    return 1.f / (1.f + expf(-x));
}

__device__ __forceinline__ float dot4(float4 a, float4 b) {
    return a.x * b.x + a.y * b.y + a.z * b.z + a.w * b.w;
}

// K1: everything with NO internal dependency, overlapped:
//   blocks [0,384):   gh = W_hh @ hidden + b_hh          (K=2048, 50.3 MB)
//   blocks [384,768): gi_emb = W_ih[:, :H] @ emb[inp]    (K=2048, 50.3 MB)
//   blocks [768,832): ctrl + s_in rows + stack_top       (row 0 of new stack)
//   blocks [832,882): new_stack rows 1..199 elementwise
// block 768 zeroes the done-counter for K2.
__global__ __launch_bounds__(256) void k_main(
        const float* __restrict__ hidden,
        const float* __restrict__ stack,
        const float* __restrict__ Wc,
        const float* __restrict__ bc,
        const float* __restrict__ Ws,
        const float* __restrict__ bs,
        const float* __restrict__ emb,
        const int* __restrict__ inp,
        const float* __restrict__ W_ih, const float* __restrict__ b_ih,
        const float* __restrict__ W_hh, const float* __restrict__ b_hh,
        float* __restrict__ ws,
        float* __restrict__ out_stack /* d_out + OO + H */) {
    int b = blockIdx.x;
    int tid = threadIdx.x;

    if (b < 768) {
        // ---- big GEMV halves (both K=2048, stack-independent) ----
        __shared__ __align__(16) float vec[H];
        bool is_gh = (b < 384);
        if (is_gh) {
            for (int k = tid; k < H; k += 256) vec[k] = hidden[k];
        } else {
            const float* er = emb + (long)inp[0] * H;
            for (int k = tid; k < H; k += 256) vec[k] = er[k];
        }
        __syncthreads();
        int wave = tid >> 6, lane = tid & 63;
        int rbase = (is_gh ? b : b - 384) * 16 + wave * 4;
        const float* W    = is_gh ? W_hh : W_ih;
        const float* bias = is_gh ? b_hh : b_ih;
        long stride = is_gh ? H : GIN;   // gi uses only first H cols of W_ih
        const float4* v4 = (const float4*)vec;
        const float4* w0 = (const float4*)(W + (rbase + 0) * stride);
        const float4* w1 = (const float4*)(W + (rbase + 1) * stride);
        const float4* w2 = (const float4*)(W + (rbase + 2) * stride);
        const float4* w3 = (const float4*)(W + (rbase + 3) * stride);
        float s0 = 0.f, s1 = 0.f, s2 = 0.f, s3 = 0.f;
        // K4 = 512 for both halves: 4 iterations of the x2-unrolled body,
        // 8 independent float4 weight loads in flight per lane.
#pragma unroll
        for (int ii = 0; ii < 4; ++ii) {
            int i = lane + ii * 128;
            int j = i + 64;
            float4 a0  = v4[i],  a1  = v4[j];
            float4 b00 = w0[i],  b01 = w0[j];
            float4 b10 = w1[i],  b11 = w1[j];
            float4 b20 = w2[i],  b21 = w2[j];
            float4 b30 = w3[i],  b31 = w3[j];
            s0 += dot4(a0, b00) + dot4(a1, b01);
            s1 += dot4(a0, b10) + dot4(a1, b11);
            s2 += dot4(a0, b20) + dot4(a1, b21);
            s3 += dot4(a0, b30) + dot4(a1, b31);
        }
        s0 = wave_reduce(s0);
        s1 = wave_reduce(s1);
        s2 = wave_reduce(s2);
        s3 = wave_reduce(s3);
        float* dst = ws + (is_gh ? GH_OFF : GI_OFF);
        if (lane == 0) {
            dst[rbase + 0] = s0 + bias[rbase + 0];
            dst[rbase + 1] = s1 + bias[rbase + 1];
            dst[rbase + 2] = s2 + bias[rbase + 2];
            dst[rbase + 3] = s3 + bias[rbase + 3];
        }
        return;
    }

    // ---- stack blocks ----
    __shared__ float sc[3];
    if (b == 768 && tid == 0) ((unsigned*)ws)[0] = 0u;   // K2 done-counter
    if (tid < 64) {
        float c0 = 0.f, c1 = 0.f, c2 = 0.f;
        for (int k = tid; k < H; k += 64) {
            float hv = hidden[k];
            c0 += hv * Wc[k];
            c1 += hv * Wc[H + k];
            c2 += hv * Wc[2 * H + k];
        }
        c0 = wave_reduce(c0); c1 = wave_reduce(c1); c2 = wave_reduce(c2);
        if (tid == 0) {
            c0 += bc[0]; c1 += bc[1]; c2 += bc[2];
            float m = fmaxf(c0, fmaxf(c1, c2));
            float e0 = expf(c0 - m), e1 = expf(c1 - m), e2 = expf(c2 - m);
            float inv = 1.f / (e0 + e1 + e2);
            sc[0] = e0 * inv;  // push
            sc[1] = e1 * inv;  // pop
            sc[2] = e2 * inv;  // noop
        }
    }
    __syncthreads();
    float a_push = sc[0], a_pop = sc[1], a_noop = sc[2];
    if (b < 832) {
        int wave = tid >> 6, lane = tid & 63;
        int row = (b - 768) * 4 + wave;            // s_in element in [0,256)
        const float4* h4 = (const float4*)hidden;
        const float4* w4 = (const float4*)(Ws + row * H);
        float sum = 0.f;
#pragma unroll
        for (int i = 0; i < 8; ++i)
            sum += dot4(h4[lane + i * 64], w4[lane + i * 64]);
        sum = wave_reduce(sum);
        if (lane == 0) {
            float s = tanhf(sum + bs[row]);
            float top = a_noop * stack[row] + a_push * s + a_pop * stack[SW + row];
            ws[STOP_OFF + row] = top;
            out_stack[row] = top;
        }
    } else {
        int rbase = 1 + (b - 832) * 4;
#pragma unroll
        for (int r = 0; r < 4; ++r) {
            int row = rbase + r;
            if (row >= SD) break;
            int idx = row * SW + tid;
            float dn = (row < SD - 1) ? stack[idx + SW] : 0.f;
            out_stack[idx] = a_noop * stack[idx] + a_push * stack[idx - SW] + a_pop * dn;
        }
    }
}

// K2: gi_stk = W_ih[:, H:H+SW] @ stack_top (384 blocks, 6.3 MB), then
// blocks 0..31 wait on a device-scope counter and finish gates + out GEMV.
// Deadlock-free without co-residency: spinners wait only on blocks that
// run to completion independently; counter zeroed by k_main (stream order).
__global__ __launch_bounds__(256) void k_fin(
        const float* __restrict__ hidden,
        const float* __restrict__ W_ih,
        const float* __restrict__ Wd, const float* __restrict__ bd,
        float* __restrict__ ws,
        float* __restrict__ d_out) {
    __shared__ __align__(16) float st[SW];
    __shared__ __align__(16) float hn[H];
    int b = blockIdx.x;
    int tid = threadIdx.x;
    if (tid < SW) st[tid] = ws[STOP_OFF + tid];
    __syncthreads();
    int wave = tid >> 6, lane = tid & 63;
    int rbase = b * 16 + wave * 4;                 // 384*16 = 6144 rows
    const float4* v4 = (const float4*)st;
    float4 a = v4[lane];                           // K=256 -> K4=64, 1 float4/lane
    const float4* w0 = (const float4*)(W_ih + (long)(rbase + 0) * GIN + H);
    const float4* w1 = (const float4*)(W_ih + (long)(rbase + 1) * GIN + H);
    const float4* w2 = (const float4*)(W_ih + (long)(rbase + 2) * GIN + H);
    const float4* w3 = (const float4*)(W_ih + (long)(rbase + 3) * GIN + H);
    float s0 = dot4(a, w0[lane]);
    float s1 = dot4(a, w1[lane]);
    float s2 = dot4(a, w2[lane]);
    float s3 = dot4(a, w3[lane]);
    s0 = wave_reduce(s0);
    s1 = wave_reduce(s1);
    s2 = wave_reduce(s2);
    s3 = wave_reduce(s3);
    if (lane == 0) {
        float* gis = ws + GIS_OFF;
        gis[rbase + 0] = s0;
        gis[rbase + 1] = s1;
        gis[rbase + 2] = s2;
        gis[rbase + 3] = s3;
    }
    __syncthreads();                   // all waves' gis stores issued & drained
    if (tid == 0) {
        __threadfence();               // agent-scope release (L2 writeback)
        atomicAdd((unsigned*)ws, 1u);
    }
    if (b >= 32) return;

    if (tid == 0) {
        while (atomicAdd((unsigned*)ws, 0u) < 384u)
            __builtin_amdgcn_s_sleep(2);
        __threadfence();               // acquire side
    }
    __syncthreads();

    const float* gi  = ws + GI_OFF;
    const float* gh  = ws + GH_OFF;
    const float* gis = ws + GIS_OFF;
    for (int i = tid; i < H; i += 256) {
        float r = sigmoidf(gi[i] + gis[i] + gh[i]);
        float z = sigmoidf(gi[H + i] + gis[H + i] + gh[H + i]);
        float n = tanhf(gi[2 * H + i] + gis[2 * H + i] + r * gh[2 * H + i]);
        float v = (1.f - z) * n + z * hidden[i];
        hn[i] = v;
        if (b == 0) d_out[OO + i] = v;
    }
    __syncthreads();
    int row = b * 4 + wave;                        // 32*4 = 128 rows
    const float4* h4  = (const float4*)hn;
    const float4* wd4 = (const float4*)(Wd + (long)row * H);
    float sum = 0.f;
#pragma unroll
    for (int i = 0; i < 8; ++i)
        sum += dot4(h4[lane + i * 64], wd4[lane + i * 64]);
    sum = wave_reduce(sum);
    if (lane == 0) d_out[row] = sum + bd[row];
}

extern "C" void kernel_launch(void* const* d_in, const int* in_sizes, int n_in,
                              void* d_out, int out_size, void* d_ws, size_t ws_size,
                              hipStream_t stream) {
    const int*   inp    = (const int*)d_in[0];
    const float* hidden = (const float*)d_in[1];
    const float* stack  = (const float*)d_in[2];
    const float* emb    = (const float*)d_in[3];
    const float* Wc     = (const float*)d_in[4];
    const float* bc     = (const float*)d_in[5];
    const float* Ws     = (const float*)d_in[6];
    const float* bs     = (const float*)d_in[7];
    const float* W_ih   = (const float*)d_in[8];
    const float* b_ih   = (const float*)d_in[9];
    const float* W_hh   = (const float*)d_in[10];
    const float* b_hh   = (const float*)d_in[11];
    const float* Wd     = (const float*)d_in[12];
    const float* bd     = (const float*)d_in[13];
    float* out = (float*)d_out;
    float* ws  = (float*)d_ws;

    k_main<<<882, 256, 0, stream>>>(hidden, stack, Wc, bc, Ws, bs, emb, inp,
                                    W_ih, b_ih, W_hh, b_hh, ws, out + OO + H);
    k_fin<<<384, 256, 0, stream>>>(hidden, W_ih, Wd, bd, ws, out);
}